// Round 9
// baseline (72.515 us; speedup 1.0000x reference)
//
#include <hip/hip_runtime.h>

// CARAFE-style fused upsampler: B=8, C=64, H=W=128, scale=2, ks=3.
// K1: channel mean (block-reduced, float4 coalesced) -> d_ws.
// K2: block = one 16x16 lo-res tile; loops over 4x 16-channel chunks with
//     double-buffered LDS + register prefetch (loads for chunk k+1 in flight
//     under compute of chunk k). Weights computed ONCE per tile (was 4x).
//     Conv weights via uniform s_load from w_off (no LDS staging).
//     LDS 56.6KB -> 2 blocks/CU; launch_bounds(256,2) -> no VGPR spill.

#define TB 256

__global__ __launch_bounds__(256, 4) void mean_kernel(
    const float* __restrict__ x, float* __restrict__ mean)
{
    __shared__ float4 part[256];
    const int tid = threadIdx.x;
    const int bid = blockIdx.x;          // 512 blocks: b = bid>>6, blk = bid&63
    const int b   = bid >> 6;
    const int blk = bid & 63;
    const int cq  = tid >> 6;            // 0..3
    const int pg  = tid & 63;            // 0..63
    const float4* xb = (const float4*)(x + ((size_t)b * 64 + cq * 16) * 16384)
                       + blk * 64 + pg;
    float4 s = make_float4(0.f, 0.f, 0.f, 0.f);
    #pragma unroll
    for (int c = 0; c < 16; ++c) {
        float4 v = xb[(size_t)c * 4096];
        s.x += v.x; s.y += v.y; s.z += v.z; s.w += v.w;
    }
    part[tid] = s;
    __syncthreads();
    if (tid < 64) {
        float4 a = part[tid], b4 = part[64 + tid], c4 = part[128 + tid], d4 = part[192 + tid];
        float4 m = make_float4((a.x + b4.x + c4.x + d4.x) * (1.f / 64),
                               (a.y + b4.y + c4.y + d4.y) * (1.f / 64),
                               (a.z + b4.z + c4.z + d4.z) * (1.f / 64),
                               (a.w + b4.w + c4.w + d4.w) * (1.f / 64));
        ((float4*)(mean + (size_t)b * 16384))[blk * 64 + tid] = m;
    }
}

__global__ __launch_bounds__(256, 2) void carafe_main(
    const float* __restrict__ x,
    const float* __restrict__ mean,
    const float* __restrict__ w_off,
    const float* __restrict__ b_off,
    float* __restrict__ out)
{
    constexpr int H = 128, W = 128, HS = 256, WS = 256;

    __shared__ float4 xs4[2][16][18][6];  // dbuf: 16ch x rows y0-1..y0+16 x cols x0-4..x0+19
    __shared__ float ms[18][19];          // mean tile, cols x0-1..x0+16

    const int tid = threadIdx.x;
    const int bid = blockIdx.x;           // b*64 + ty*8 + tx
    const int b  = bid >> 6;
    const int ty = (bid >> 3) & 7;
    const int tx = bid & 7;
    const int y0 = ty * 16, x0 = tx * 16;

    // ---- chunk-invariant staging constants (7 float4 per thread) ----
    int  goff[7]; int ldso[7]; bool val[7];
    #pragma unroll
    for (int it = 0; it < 7; ++it) {
        const int idx = tid + it * TB;
        const int c   = idx / 108;
        const int rem = idx - c * 108;
        const int r   = rem / 6;
        const int q   = rem - r * 6;
        const int gy  = y0 - 1 + r;
        const int cb  = x0 - 4 + 4 * q;
        val[it]  = (idx < 1728) && ((unsigned)gy < (unsigned)H) && ((unsigned)cb < (unsigned)W);
        goff[it] = c * (H * W) + gy * W + cb;
        ldso[it] = (c * 18 + r) * 6 + q;          // float4 index within one buf
    }
    const bool wr6 = (tid < 192);                 // idx<1728 guard for it=6

    const float* xb = x + (size_t)b * 64 * (H * W);
    float4* bufA = &xs4[0][0][0][0];
    float4* bufB = &xs4[1][0][0][0];

    // ---- prologue: issue chunk0 loads ----
    float4 pf[7];
    #pragma unroll
    for (int it = 0; it < 7; ++it)
        pf[it] = val[it] ? *(const float4*)(xb + goff[it]) : make_float4(0.f, 0.f, 0.f, 0.f);

    // stage mean tile (zero outside image)
    const float* mb = mean + (size_t)b * (H * W);
    #pragma unroll
    for (int it = 0; it < 2; ++it) {
        const int idx = tid + it * TB;
        if (idx < 324) {
            const int r = idx / 18, col = idx - r * 18;
            const int gy = y0 - 1 + r, gx = x0 - 1 + col;
            float v = 0.f;
            if ((unsigned)gy < (unsigned)H && (unsigned)gx < (unsigned)W)
                v = mb[gy * W + gx];
            ms[r][col] = v;
        }
    }

    // write chunk0 -> buf0
    #pragma unroll
    for (int it = 0; it < 6; ++it) bufA[ldso[it]] = pf[it];
    if (wr6) bufA[ldso[6]] = pf[6];

    // issue chunk1 loads
    #pragma unroll
    for (int it = 0; it < 7; ++it)
        pf[it] = val[it] ? *(const float4*)(xb + 16 * (H * W) + goff[it]) : make_float4(0.f, 0.f, 0.f, 0.f);

    __syncthreads();

    // ---- per-thread pixel mapping + weights (ONCE per tile) ----
    const int hy  = tid >> 3;            // 0..31 local hi-res row
    const int hq  = tid & 7;             // column group (4 px)
    const int yr  = hy >> 1;             // 0..15 local lo-res row
    const int podd = hy & 1;
    const int Yg  = 2 * y0 + hy;
    const int Xg0 = 2 * x0 + hq * 4;

    float m[3][4];
    #pragma unroll
    for (int r = 0; r < 3; ++r)
        #pragma unroll
        for (int cl = 0; cl < 4; ++cl)
            m[r][cl] = ms[yr + r][2 * hq + cl];

    // parity-resolved conv row sources (even rows {0,0,1,1,2}, odd {0,1,1,2,2})
    float mrp[5][4];
    #pragma unroll
    for (int cl = 0; cl < 4; ++cl) {
        mrp[0][cl] = m[0][cl];
        mrp[1][cl] = podd ? m[1][cl] : m[0][cl];
        mrp[2][cl] = m[1][cl];
        mrp[3][cl] = podd ? m[2][cl] : m[1][cl];
        mrp[4][cl] = m[2][cl];
    }

    const float b0 = b_off[0], b1 = b_off[1];
    float wgt[4][9];
    #pragma unroll
    for (int j = 0; j < 4; ++j) {
        float o0 = 0.f, o1 = 0.f;
        #pragma unroll
        for (int p = 0; p < 5; ++p)
            #pragma unroll
            for (int q = 0; q < 5; ++q) {
                const int cl = ((j + q - 2) >> 1) + 1;   // compile-time
                o0 = fmaf(w_off[p * 5 + q],      mrp[p][cl], o0);
                o1 = fmaf(w_off[25 + p * 5 + q], mrp[p][cl], o1);
            }
        const float off0 = tanhf(o0 + b0) * 0.25f;
        const float off1 = tanhf(o1 + b1) * 0.25f;
        const float s0 = (podd ? 0.25f : -0.25f) + off0;
        const float s1 = ((j & 1) ? 0.25f : -0.25f) + off1;

        const int jc = 1 + (j >> 1);
        const float mctr = m[1][jc];

        float lg[9];
        float lmax = -1e30f;
        #pragma unroll
        for (int k = 0; k < 9; ++k) {
            const int di = k / 3 - 1, dj = k % 3 - 1;
            const float d0 = s0 - (float)di;
            const float d1 = s1 - (float)dj;
            const float kern = 1.0f / fmaf(d0, d0, fmaf(d1, d1, 0.5f));
            const float gd = m[1 + di][jc + dj] - mctr;
            const float g  = 1.0f / fmaf(gd, gd, 1.0f);
            lg[k] = g * kern;
            lmax = fmaxf(lmax, lg[k]);
        }
        float ssum = 0.f;
        #pragma unroll
        for (int k = 0; k < 9; ++k) { lg[k] = __expf(lg[k] - lmax); ssum += lg[k]; }
        const float inv = 1.f / ssum;
        #pragma unroll
        for (int k = 0; k < 9; ++k) wgt[j][k] = lg[k] * inv;
    }

    // ---- main loop: 4 chunks, dbuf (compute k from buf[k&1], k+1 in pf) ----
    const float2* xs2base = (const float2*)&xs4[0][0][0][0];  // per-buf: 3456 float2
    float* ob = out + ((size_t)b * 64 * HS + Yg) * WS + Xg0;

    #pragma unroll
    for (int ch = 0; ch < 4; ++ch) {
        const int cur = ch & 1;
        const float2* xs2 = xs2base + cur * 3456;
        float* oc = ob + (size_t)ch * 16 * HS * WS;

        #pragma unroll 4
        for (int c = 0; c < 16; ++c) {
            float xv[3][4];
            #pragma unroll
            for (int r = 0; r < 3; ++r) {
                const int rb = ((c * 18) + yr + r) * 12 + hq;   // float2 index
                const float2 f0 = xs2[rb + 1];   // cols 2hq+2, 2hq+3
                const float2 f1 = xs2[rb + 2];   // cols 2hq+4, 2hq+5
                const float2 f2 = xs2[rb + 3];   // cols 2hq+6, 2hq+7
                xv[r][0] = f0.y; xv[r][1] = f1.x; xv[r][2] = f1.y; xv[r][3] = f2.x;
            }
            float a[4];
            #pragma unroll
            for (int j = 0; j < 4; ++j) {
                const int px = j >> 1;
                float s = 0.f;
                #pragma unroll
                for (int di = 0; di < 3; ++di)
                    #pragma unroll
                    for (int dj = 0; dj < 3; ++dj)
                        s = fmaf(wgt[j][di * 3 + dj], xv[di][px + dj], s);
                a[j] = s;
            }
            *reinterpret_cast<float4*>(oc + (size_t)c * HS * WS) =
                make_float4(a[0], a[1], a[2], a[3]);
        }

        if (ch < 3) {
            __syncthreads();                       // all reads of buf[cur^1] (iter ch-1) done
            float4* bufn = cur ? bufA : bufB;      // buf[(ch+1)&1]
            #pragma unroll
            for (int it = 0; it < 6; ++it) bufn[ldso[it]] = pf[it];
            if (wr6) bufn[ldso[6]] = pf[6];
            if (ch < 2) {                          // issue loads for chunk ch+2
                const float* xc = xb + (size_t)(ch + 2) * 16 * (H * W);
                #pragma unroll
                for (int it = 0; it < 7; ++it)
                    pf[it] = val[it] ? *(const float4*)(xc + goff[it]) : make_float4(0.f, 0.f, 0.f, 0.f);
            }
            __syncthreads();                       // buf[(ch+1)&1] visible
        }
    }
}

extern "C" void kernel_launch(void* const* d_in, const int* in_sizes, int n_in,
                              void* d_out, int out_size, void* d_ws, size_t ws_size,
                              hipStream_t stream) {
    const float* x  = (const float*)d_in[0];
    const float* w  = (const float*)d_in[1];
    const float* bo = (const float*)d_in[2];
    float* out  = (float*)d_out;
    float* mean = (float*)d_ws;            // 8*128*128 floats = 512 KB

    mean_kernel<<<512, TB, 0, stream>>>(x, mean);
    // grid: 8 batches * 8x8 tiles (one tile per block, 4 channel chunks inside)
    carafe_main<<<512, TB, 0, stream>>>(x, mean, w, bo, out);
}

// Round 10
// 62.254 us; speedup vs baseline: 1.1648x; 1.1648x over previous
//
#include <hip/hip_runtime.h>

// CARAFE-style fused upsampler: B=8, C=64, H=W=128, scale=2, ks=3.
// K1: channel mean (block-reduced, float4 coalesced) -> d_ws.
// K2: (batch, 16x16 lo-res tile, 16-ch group), 2048 blocks (round-8 base) +
//   (1) fast-math weight path: v_rcp_f32 + tanh via exp2 (hipcc w/o fast-math
//       emits ~10-instr div chains and a ~40-instr tanhf libcall otherwise);
//   (2) T14 stage split: x-tile loads issued BEFORE weight math, LDS-written
//       after it -- HBM latency hides under ~1500 cyc of weight VALU.

#define TB 256

__device__ __forceinline__ float frcp(float x) { return __builtin_amdgcn_rcpf(x); }
__device__ __forceinline__ float ftanh(float x) {
    // tanh(x) = 1 - 2/(e^{2x}+1); |err| ~1e-6, threshold headroom ~5x
    const float e = __expf(2.0f * x);
    return 1.0f - 2.0f * frcp(e + 1.0f);
}

__global__ __launch_bounds__(256, 4) void mean_kernel(
    const float* __restrict__ x, float* __restrict__ mean)
{
    __shared__ float4 part[256];
    const int tid = threadIdx.x;
    const int bid = blockIdx.x;          // 512 blocks: b = bid>>6, blk = bid&63
    const int b   = bid >> 6;
    const int blk = bid & 63;
    const int cq  = tid >> 6;            // 0..3
    const int pg  = tid & 63;            // 0..63
    const float4* xb = (const float4*)(x + ((size_t)b * 64 + cq * 16) * 16384)
                       + blk * 64 + pg;
    float4 s = make_float4(0.f, 0.f, 0.f, 0.f);
    #pragma unroll
    for (int c = 0; c < 16; ++c) {
        float4 v = xb[(size_t)c * 4096];
        s.x += v.x; s.y += v.y; s.z += v.z; s.w += v.w;
    }
    part[tid] = s;
    __syncthreads();
    if (tid < 64) {
        float4 a = part[tid], b4 = part[64 + tid], c4 = part[128 + tid], d4 = part[192 + tid];
        float4 m = make_float4((a.x + b4.x + c4.x + d4.x) * (1.f / 64),
                               (a.y + b4.y + c4.y + d4.y) * (1.f / 64),
                               (a.z + b4.z + c4.z + d4.z) * (1.f / 64),
                               (a.w + b4.w + c4.w + d4.w) * (1.f / 64));
        ((float4*)(mean + (size_t)b * 16384))[blk * 64 + tid] = m;
    }
}

__global__ __launch_bounds__(256, 4) void carafe_main(
    const float* __restrict__ x,
    const float* __restrict__ mean,
    const float* __restrict__ w_off,
    const float* __restrict__ b_off,
    float* __restrict__ out)
{
    constexpr int H = 128, W = 128, HS = 256, WS = 256;

    __shared__ float4 xs4[16][18][6];   // rows y0-1..y0+16, cols x0-4..x0+19
    __shared__ float ms[18][19];        // mean tile, cols x0-1..x0+16
    const float2* xs2 = (const float2*)&xs4[0][0][0];   // [16][18][12]

    const int tid = threadIdx.x;
    const int bid = blockIdx.x;
    // bid = b*256 + ty*32 + tx*4 + cg
    const int b  = bid >> 8;
    const int t  = bid & 255;
    const int ty = t >> 5;
    const int tx = (t >> 2) & 7;
    const int cg = t & 3;
    const int y0 = ty * 16, x0 = tx * 16;
    const int c0 = cg * 16;

    // ---- issue mean-tile loads (registers) ----
    const float* mb = mean + (size_t)b * (H * W);
    float mval[2];
    #pragma unroll
    for (int it = 0; it < 2; ++it) {
        const int idx = tid + it * TB;
        mval[it] = 0.f;
        if (idx < 324) {
            const int r = idx / 18, col = idx - r * 18;
            const int gy = y0 - 1 + r, gx = x0 - 1 + col;
            if ((unsigned)gy < (unsigned)H && (unsigned)gx < (unsigned)W)
                mval[it] = mb[gy * W + gx];
        }
    }

    // ---- issue x-tile loads (7 float4), written to LDS only after weights ----
    const float* xb = x + ((size_t)b * 64 + c0) * (H * W);
    float4 pf[7];
    #pragma unroll
    for (int it = 0; it < 7; ++it) {
        const int idx = tid + it * TB;
        const int c   = idx / 108;
        const int rem = idx - c * 108;
        const int r   = rem / 6;
        const int q   = rem - r * 6;
        const int gy  = y0 - 1 + r;
        const int cb  = x0 - 4 + 4 * q;
        const bool v  = (idx < 1728) && ((unsigned)gy < (unsigned)H) && ((unsigned)cb < (unsigned)W);
        pf[it] = v ? *(const float4*)(xb + (c * H + gy) * W + cb)
                   : make_float4(0.f, 0.f, 0.f, 0.f);
    }

    // ---- write + publish mean tile ----
    #pragma unroll
    for (int it = 0; it < 2; ++it) {
        const int idx = tid + it * TB;
        if (idx < 324) {
            const int r = idx / 18, col = idx - r * 18;
            ms[r][col] = mval[it];
        }
    }
    __syncthreads();

    // ---- weight math (x loads still in flight underneath) ----
    const int hy  = tid >> 3;            // 0..31 local hi-res row
    const int hq  = tid & 7;             // column group (4 px)
    const int yr  = hy >> 1;             // 0..15 local lo-res row
    const int podd = hy & 1;
    const int Yg  = 2 * y0 + hy;
    const int Xg0 = 2 * x0 + hq * 4;

    float m[3][4];
    #pragma unroll
    for (int r = 0; r < 3; ++r)
        #pragma unroll
        for (int cl = 0; cl < 4; ++cl)
            m[r][cl] = ms[yr + r][2 * hq + cl];

    // parity-resolved conv row sources (even rows {0,0,1,1,2}, odd {0,1,1,2,2})
    float mrp[5][4];
    #pragma unroll
    for (int cl = 0; cl < 4; ++cl) {
        mrp[0][cl] = m[0][cl];
        mrp[1][cl] = podd ? m[1][cl] : m[0][cl];
        mrp[2][cl] = m[1][cl];
        mrp[3][cl] = podd ? m[2][cl] : m[1][cl];
        mrp[4][cl] = m[2][cl];
    }

    const float b0 = b_off[0], b1 = b_off[1];
    float wgt[4][9];
    #pragma unroll
    for (int j = 0; j < 4; ++j) {
        float o0 = 0.f, o1 = 0.f;
        #pragma unroll
        for (int p = 0; p < 5; ++p)
            #pragma unroll
            for (int q = 0; q < 5; ++q) {
                const int cl = ((j + q - 2) >> 1) + 1;   // compile-time
                o0 = fmaf(w_off[p * 5 + q],      mrp[p][cl], o0);
                o1 = fmaf(w_off[25 + p * 5 + q], mrp[p][cl], o1);
            }
        const float off0 = ftanh(o0 + b0) * 0.25f;
        const float off1 = ftanh(o1 + b1) * 0.25f;
        const float s0 = (podd ? 0.25f : -0.25f) + off0;
        const float s1 = ((j & 1) ? 0.25f : -0.25f) + off1;

        const int jc = 1 + (j >> 1);
        const float mctr = m[1][jc];

        float lg[9];
        float lmax = -1e30f;
        #pragma unroll
        for (int k = 0; k < 9; ++k) {
            const int di = k / 3 - 1, dj = k % 3 - 1;
            const float d0 = s0 - (float)di;
            const float d1 = s1 - (float)dj;
            const float kern = frcp(fmaf(d0, d0, fmaf(d1, d1, 0.5f)));
            const float gd = m[1 + di][jc + dj] - mctr;
            const float g  = frcp(fmaf(gd, gd, 1.0f));
            lg[k] = g * kern;
            lmax = fmaxf(lmax, lg[k]);
        }
        float ssum = 0.f;
        #pragma unroll
        for (int k = 0; k < 9; ++k) { lg[k] = __expf(lg[k] - lmax); ssum += lg[k]; }
        const float inv = frcp(ssum);
        #pragma unroll
        for (int k = 0; k < 9; ++k) wgt[j][k] = lg[k] * inv;
    }

    // ---- write + publish x tile (loads have drained under weight math) ----
    float4* xsl = &xs4[0][0][0];
    #pragma unroll
    for (int it = 0; it < 7; ++it) {
        const int idx = tid + it * TB;
        if (it < 6 || idx < 1728) {
            const int c   = idx / 108;
            const int rem = idx - c * 108;
            const int r   = rem / 6;
            const int q   = rem - r * 6;
            xsl[(c * 18 + r) * 6 + q] = pf[it];
        }
    }
    __syncthreads();

    // ---- CARAFE: 16 channels; taps = 3 float2 reads per row (8B aligned) ----
    float* ob = out + (((size_t)b * 64 + c0) * HS + Yg) * WS + Xg0;
    #pragma unroll 4
    for (int c = 0; c < 16; ++c) {
        float xv[3][4];
        #pragma unroll
        for (int r = 0; r < 3; ++r) {
            const int rb = ((c * 18) + yr + r) * 12 + hq;   // float2 index
            const float2 f0 = xs2[rb + 1];   // cols 2hq+2, 2hq+3
            const float2 f1 = xs2[rb + 2];   // cols 2hq+4, 2hq+5
            const float2 f2 = xs2[rb + 3];   // cols 2hq+6, 2hq+7
            xv[r][0] = f0.y; xv[r][1] = f1.x; xv[r][2] = f1.y; xv[r][3] = f2.x;
        }
        float a[4];
        #pragma unroll
        for (int j = 0; j < 4; ++j) {
            const int px = j >> 1;
            float s = 0.f;
            #pragma unroll
            for (int di = 0; di < 3; ++di)
                #pragma unroll
                for (int dj = 0; dj < 3; ++dj)
                    s = fmaf(wgt[j][di * 3 + dj], xv[di][px + dj], s);
            a[j] = s;
        }
        *reinterpret_cast<float4*>(ob + (size_t)c * HS * WS) =
            make_float4(a[0], a[1], a[2], a[3]);
    }
}

extern "C" void kernel_launch(void* const* d_in, const int* in_sizes, int n_in,
                              void* d_out, int out_size, void* d_ws, size_t ws_size,
                              hipStream_t stream) {
    const float* x  = (const float*)d_in[0];
    const float* w  = (const float*)d_in[1];
    const float* bo = (const float*)d_in[2];
    float* out  = (float*)d_out;
    float* mean = (float*)d_ws;            // 8*128*128 floats = 512 KB

    mean_kernel<<<512, TB, 0, stream>>>(x, mean);
    // grid: 8 batches * 8x8 tiles * 4 channel groups
    carafe_main<<<2048, TB, 0, stream>>>(x, mean, w, bo, out);
}

// Round 11
// 61.124 us; speedup vs baseline: 1.1864x; 1.0185x over previous
//
#include <hip/hip_runtime.h>

// CARAFE-style fused upsampler: B=8, C=64, H=W=128, scale=2, ks=3.
// K1: channel mean (block-reduced, float4 coalesced) -> d_ws.
// K2: (batch, 16x16 lo-res tile, 16-ch group), 2048 blocks; fast-math weight
//     path (v_rcp_f32, tanh via expf); T14 stage split (x loads in flight
//     under weight math). Round 11: column-aggregated 5x5 conv (uniform
//     coeffs -> 120 FMA/thread instead of 400) + softmax without max-sub
//     (lg in (0,2], exp<=7.4: overflow-free, bit-equivalent to ~1e-7).

#define TB 256

__device__ __forceinline__ float frcp(float x) { return __builtin_amdgcn_rcpf(x); }
__device__ __forceinline__ float ftanh(float x) {
    // tanh(x) = 1 - 2/(e^{2x}+1); |err| ~1e-6, threshold headroom ~5x
    const float e = __expf(2.0f * x);
    return 1.0f - 2.0f * frcp(e + 1.0f);
}

__global__ __launch_bounds__(256, 4) void mean_kernel(
    const float* __restrict__ x, float* __restrict__ mean)
{
    __shared__ float4 part[256];
    const int tid = threadIdx.x;
    const int bid = blockIdx.x;          // 512 blocks: b = bid>>6, blk = bid&63
    const int b   = bid >> 6;
    const int blk = bid & 63;
    const int cq  = tid >> 6;            // 0..3
    const int pg  = tid & 63;            // 0..63
    const float4* xb = (const float4*)(x + ((size_t)b * 64 + cq * 16) * 16384)
                       + blk * 64 + pg;
    float4 s = make_float4(0.f, 0.f, 0.f, 0.f);
    #pragma unroll
    for (int c = 0; c < 16; ++c) {
        float4 v = xb[(size_t)c * 4096];
        s.x += v.x; s.y += v.y; s.z += v.z; s.w += v.w;
    }
    part[tid] = s;
    __syncthreads();
    if (tid < 64) {
        float4 a = part[tid], b4 = part[64 + tid], c4 = part[128 + tid], d4 = part[192 + tid];
        float4 m = make_float4((a.x + b4.x + c4.x + d4.x) * (1.f / 64),
                               (a.y + b4.y + c4.y + d4.y) * (1.f / 64),
                               (a.z + b4.z + c4.z + d4.z) * (1.f / 64),
                               (a.w + b4.w + c4.w + d4.w) * (1.f / 64));
        ((float4*)(mean + (size_t)b * 16384))[blk * 64 + tid] = m;
    }
}

__global__ __launch_bounds__(256, 4) void carafe_main(
    const float* __restrict__ x,
    const float* __restrict__ mean,
    const float* __restrict__ w_off,
    const float* __restrict__ b_off,
    float* __restrict__ out)
{
    constexpr int H = 128, W = 128, HS = 256, WS = 256;

    __shared__ float4 xs4[16][18][6];   // rows y0-1..y0+16, cols x0-4..x0+19
    __shared__ float ms[18][19];        // mean tile, cols x0-1..x0+16
    const float2* xs2 = (const float2*)&xs4[0][0][0];   // [16][18][12]

    const int tid = threadIdx.x;
    const int bid = blockIdx.x;
    // bid = b*256 + ty*32 + tx*4 + cg
    const int b  = bid >> 8;
    const int t  = bid & 255;
    const int ty = t >> 5;
    const int tx = (t >> 2) & 7;
    const int cg = t & 3;
    const int y0 = ty * 16, x0 = tx * 16;
    const int c0 = cg * 16;

    // ---- issue mean-tile loads (registers) ----
    const float* mb = mean + (size_t)b * (H * W);
    float mval[2];
    #pragma unroll
    for (int it = 0; it < 2; ++it) {
        const int idx = tid + it * TB;
        mval[it] = 0.f;
        if (idx < 324) {
            const int r = idx / 18, col = idx - r * 18;
            const int gy = y0 - 1 + r, gx = x0 - 1 + col;
            if ((unsigned)gy < (unsigned)H && (unsigned)gx < (unsigned)W)
                mval[it] = mb[gy * W + gx];
        }
    }

    // ---- issue x-tile loads (7 float4), written to LDS only after weights ----
    const float* xb = x + ((size_t)b * 64 + c0) * (H * W);
    float4 pf[7];
    #pragma unroll
    for (int it = 0; it < 7; ++it) {
        const int idx = tid + it * TB;
        const int c   = idx / 108;
        const int rem = idx - c * 108;
        const int r   = rem / 6;
        const int q   = rem - r * 6;
        const int gy  = y0 - 1 + r;
        const int cb  = x0 - 4 + 4 * q;
        const bool v  = (idx < 1728) && ((unsigned)gy < (unsigned)H) && ((unsigned)cb < (unsigned)W);
        pf[it] = v ? *(const float4*)(xb + (c * H + gy) * W + cb)
                   : make_float4(0.f, 0.f, 0.f, 0.f);
    }

    // ---- write + publish mean tile ----
    #pragma unroll
    for (int it = 0; it < 2; ++it) {
        const int idx = tid + it * TB;
        if (idx < 324) {
            const int r = idx / 18, col = idx - r * 18;
            ms[r][col] = mval[it];
        }
    }
    __syncthreads();

    // ---- weight math (x loads still in flight underneath) ----
    const int hy  = tid >> 3;            // 0..31 local hi-res row
    const int hq  = tid & 7;             // column group (4 px)
    const int yr  = hy >> 1;             // 0..15 local lo-res row
    const int podd = hy & 1;
    const int Yg  = 2 * y0 + hy;
    const int Xg0 = 2 * x0 + hq * 4;

    float m[3][4];
    #pragma unroll
    for (int r = 0; r < 3; ++r)
        #pragma unroll
        for (int cl = 0; cl < 4; ++cl)
            m[r][cl] = ms[yr + r][2 * hq + cl];

    // parity-resolved conv row sources (even rows {0,0,1,1,2}, odd {0,1,1,2,2})
    float mrp[5][4];
    #pragma unroll
    for (int cl = 0; cl < 4; ++cl) {
        mrp[0][cl] = m[0][cl];
        mrp[1][cl] = podd ? m[1][cl] : m[0][cl];
        mrp[2][cl] = m[1][cl];
        mrp[3][cl] = podd ? m[2][cl] : m[1][cl];
        mrp[4][cl] = m[2][cl];
    }

    // column-aggregated conv coefficients -- THREAD-UNIFORM (pure w_off fns):
    // even px (j=0,2): cols d+{0,1,2} weighted {w0+w1, w2+w3, w4}
    // odd  px (j=1,3): cols d+{0,1,2} weighted {w0, w1+w2, w3+w4}
    float ce[2][5][3], co_[2][5][3];     // [out0/out1][p][t]
    #pragma unroll
    for (int o = 0; o < 2; ++o)
        #pragma unroll
        for (int p = 0; p < 5; ++p) {
            const float w0 = w_off[o * 25 + p * 5 + 0];
            const float w1 = w_off[o * 25 + p * 5 + 1];
            const float w2 = w_off[o * 25 + p * 5 + 2];
            const float w3 = w_off[o * 25 + p * 5 + 3];
            const float w4 = w_off[o * 25 + p * 5 + 4];
            ce[o][p][0]  = w0 + w1;  ce[o][p][1]  = w2 + w3;  ce[o][p][2]  = w4;
            co_[o][p][0] = w0;       co_[o][p][1] = w1 + w2;  co_[o][p][2] = w3 + w4;
        }

    const float b0 = b_off[0], b1 = b_off[1];
    float wgt[4][9];
    #pragma unroll
    for (int j = 0; j < 4; ++j) {
        const int d = j >> 1;
        float o0 = 0.f, o1 = 0.f;
        if (j & 1) {
            #pragma unroll
            for (int p = 0; p < 5; ++p)
                #pragma unroll
                for (int tt = 0; tt < 3; ++tt) {
                    o0 = fmaf(co_[0][p][tt], mrp[p][d + tt], o0);
                    o1 = fmaf(co_[1][p][tt], mrp[p][d + tt], o1);
                }
        } else {
            #pragma unroll
            for (int p = 0; p < 5; ++p)
                #pragma unroll
                for (int tt = 0; tt < 3; ++tt) {
                    o0 = fmaf(ce[0][p][tt], mrp[p][d + tt], o0);
                    o1 = fmaf(ce[1][p][tt], mrp[p][d + tt], o1);
                }
        }
        const float off0 = ftanh(o0 + b0) * 0.25f;
        const float off1 = ftanh(o1 + b1) * 0.25f;
        const float s0 = (podd ? 0.25f : -0.25f) + off0;
        const float s1 = ((j & 1) ? 0.25f : -0.25f) + off1;

        const int jc = 1 + d;
        const float mctr = m[1][jc];

        // lg = g*kern in (0,2] -> exp in (1,7.4]: no max-subtraction needed
        float ssum = 0.f;
        float lg[9];
        #pragma unroll
        for (int k = 0; k < 9; ++k) {
            const int di = k / 3 - 1, dj = k % 3 - 1;
            const float d0 = s0 - (float)di;
            const float d1 = s1 - (float)dj;
            const float kern = frcp(fmaf(d0, d0, fmaf(d1, d1, 0.5f)));
            const float gd = m[1 + di][jc + dj] - mctr;
            const float g  = frcp(fmaf(gd, gd, 1.0f));
            lg[k] = __expf(g * kern);
            ssum += lg[k];
        }
        const float inv = frcp(ssum);
        #pragma unroll
        for (int k = 0; k < 9; ++k) wgt[j][k] = lg[k] * inv;
    }

    // ---- write + publish x tile (loads have drained under weight math) ----
    float4* xsl = &xs4[0][0][0];
    #pragma unroll
    for (int it = 0; it < 7; ++it) {
        const int idx = tid + it * TB;
        if (it < 6 || idx < 1728) {
            const int c   = idx / 108;
            const int rem = idx - c * 108;
            const int r   = rem / 6;
            const int q   = rem - r * 6;
            xsl[(c * 18 + r) * 6 + q] = pf[it];
        }
    }
    __syncthreads();

    // ---- CARAFE: 16 channels; taps = 3 float2 reads per row (8B aligned) ----
    float* ob = out + (((size_t)b * 64 + c0) * HS + Yg) * WS + Xg0;
    #pragma unroll 4
    for (int c = 0; c < 16; ++c) {
        float xv[3][4];
        #pragma unroll
        for (int r = 0; r < 3; ++r) {
            const int rb = ((c * 18) + yr + r) * 12 + hq;   // float2 index
            const float2 f0 = xs2[rb + 1];   // cols 2hq+2, 2hq+3
            const float2 f1 = xs2[rb + 2];   // cols 2hq+4, 2hq+5
            const float2 f2 = xs2[rb + 3];   // cols 2hq+6, 2hq+7
            xv[r][0] = f0.y; xv[r][1] = f1.x; xv[r][2] = f1.y; xv[r][3] = f2.x;
        }
        float a[4];
        #pragma unroll
        for (int j = 0; j < 4; ++j) {
            const int px = j >> 1;
            float s = 0.f;
            #pragma unroll
            for (int di = 0; di < 3; ++di)
                #pragma unroll
                for (int dj = 0; dj < 3; ++dj)
                    s = fmaf(wgt[j][di * 3 + dj], xv[di][px + dj], s);
            a[j] = s;
        }
        *reinterpret_cast<float4*>(ob + (size_t)c * HS * WS) =
            make_float4(a[0], a[1], a[2], a[3]);
    }
}

extern "C" void kernel_launch(void* const* d_in, const int* in_sizes, int n_in,
                              void* d_out, int out_size, void* d_ws, size_t ws_size,
                              hipStream_t stream) {
    const float* x  = (const float*)d_in[0];
    const float* w  = (const float*)d_in[1];
    const float* bo = (const float*)d_in[2];
    float* out  = (float*)d_out;
    float* mean = (float*)d_ws;            // 8*128*128 floats = 512 KB

    mean_kernel<<<512, TB, 0, stream>>>(x, mean);
    // grid: 8 batches * 8x8 tiles * 4 channel groups
    carafe_main<<<2048, TB, 0, stream>>>(x, mean, w, bo, out);
}